// Round 20
// baseline (2790.354 us; speedup 1.0000x reference)
//
#include <hip/hip_runtime.h>

typedef __attribute__((ext_vector_type(4))) float f32x4;
typedef __attribute__((ext_vector_type(8))) short bf16x8;
typedef unsigned short u16;
typedef unsigned int u32;
typedef __attribute__((ext_vector_type(4))) unsigned short u16x4;

#define EPS 1.1920929e-07f
#define S 1024
#define D 1024
#define NV 151936
#define NCYC 28
#define SMEM_BYTES 49152

__device__ __forceinline__ u16 f2bf(float f) {  // RNE
  u32 u = __float_as_uint(f);
  return (u16)((u + 0x7fffu + ((u >> 16) & 1u)) >> 16);
}
__device__ __forceinline__ float bf2f(u16 h) {
  return __uint_as_float((u32)h << 16);
}
struct bfpair { u16 h, l; };
__device__ __forceinline__ bfpair split_bf(float v) {
  bfpair r;
  r.h = f2bf(v);
  r.l = f2bf(v - bf2f(r.h));
  return r;
}

__device__ __forceinline__ void gl16(const void* g, void* s) {
  __builtin_amdgcn_global_load_lds((const __attribute__((address_space(1))) u32*)g,
                                   (__attribute__((address_space(3))) u32*)s, 16, 0, 0);
}

// safe for repeated calls (sync protects sbuf reuse)
__device__ __forceinline__ float block_sum256(float v, float* sbuf) {
  #pragma unroll
  for (int off = 32; off; off >>= 1) v += __shfl_down(v, off);
  int lane = threadIdx.x & 63, w = threadIdx.x >> 6;
  __syncthreads();
  if (lane == 0) sbuf[w] = v;
  __syncthreads();
  return sbuf[0] + sbuf[1] + sbuf[2] + sbuf[3];
}

// split-convert a range with a block sub-grid [blkbase, blkbase+nblk)
__device__ void cvt2_range(const float* __restrict__ src, u16* __restrict__ dh,
                           u16* __restrict__ dl, size_t n4, int blkbase, int nblk) {
  for (size_t i = (size_t)(blockIdx.x - blkbase) * 256 + threadIdx.x; i < n4;
       i += (size_t)nblk * 256) {
    f32x4 v = ((const f32x4*)src)[i];
    u16x4 oh, ol;
    #pragma unroll
    for (int e = 0; e < 4; ++e) { bfpair p = split_bf(v[e]); oh[e] = p.h; ol[e] = p.l; }
    ((u16x4*)dh)[i] = oh;
    ((u16x4*)dl)[i] = ol;
  }
}

// side-work: convert one chunk of lm weights (chunk in [0, NCYC*2))
__device__ void side_cvt(const float* __restrict__ src, u16* __restrict__ dst,
                         int chunk, int blkbase) {
  if (!src) return;
  const size_t n4 = (size_t)NV * D / 4;
  const size_t per = (n4 + (size_t)(NCYC * 2) - 1) / (size_t)(NCYC * 2);
  size_t lo = (size_t)chunk * per;
  size_t hi = lo + per;
  if (hi > n4) hi = n4;
  const size_t nb = (size_t)(gridDim.x - blkbase);
  for (size_t i = lo + (size_t)(blockIdx.x - blkbase) * 256 + threadIdx.x; i < hi;
       i += nb * 256) {
    f32x4 v = ((const f32x4*)src)[i];
    u16x4 o;
    #pragma unroll
    for (int e = 0; e < 4; ++e) o[e] = f2bf(v[e]);
    ((u16x4*)dst)[i] = o;
  }
}

// ================= device phases =================

// gather + initial colpart; blocks 0..255
__device__ void gather_phase(const int* tokens, const float* embed,
                             float* x, u16* xh, u16* xl, float* cp) {
  const int t = threadIdx.x;
  f32x4 creg = 0.f;
  for (int rr = 0; rr < 4; ++rr) {
    int s = blockIdx.x * 4 + rr;
    int tok = tokens[s];
    f32x4 v = ((const f32x4*)(embed + (size_t)tok * D))[t];
    u16x4 oh, ol;
    #pragma unroll
    for (int e = 0; e < 4; ++e) { bfpair p = split_bf(v[e]); oh[e] = p.h; ol[e] = p.l; }
    ((f32x4*)(x + (size_t)s * D))[t] = v;
    ((u16x4*)(xh + (size_t)s * D))[t] = oh;
    ((u16x4*)(xl + (size_t)s * D))[t] = ol;
    creg += v;
  }
  *(f32x4*)(cp + (size_t)blockIdx.x * D + t * 4) = creg;
}

// 64x64-tile split-bf16 GEMM, 256 tiles, DOUBLE-buffered (gate; 1 block/CU grid)
template <bool CADD>
__device__ void gemm64_dbuf(char* smem, const u16* Ah_, const u16* Al_,
                            const u16* Bh_, const u16* Bl_, int K,
                            float* xout, u16* xho, u16* xlo, float* Cout) {
  const int t = threadIdx.x;
  u16* Ash = (u16*)smem;          // [2][4096] each operand
  u16* Asl = Ash + 8192;
  u16* Bsh = Asl + 8192;
  u16* Bsl = Bsh + 8192;
  const int wave = t >> 6, lane = t & 63;
  const int fr = lane & 15, kb = lane >> 4;
  const int sr = t >> 3, skc = (t & 7) << 3;
  const int sswz = skc ^ ((sr & 7) << 3);
  const int m0 = (blockIdx.x >> 4) * 64, n0 = (blockIdx.x & 15) * 64;
  f32x4 acc[4];
  #pragma unroll
  for (int j = 0; j < 4; ++j) acc[j] = 0.f;

  auto stage = [&](int buf, int k0) {
    #pragma unroll
    for (int it = 0; it < 2; ++it) {
      int r = it * 32 + sr;
      size_t ga = (size_t)(m0 + r) * K + k0 + sswz;
      size_t gb = (size_t)(n0 + r) * K + k0 + sswz;
      int so = buf * 4096 + r * 64 + skc;
      gl16(Ah_ + ga, Ash + so);
      gl16(Al_ + ga, Asl + so);
      gl16(Bh_ + gb, Bsh + so);
      gl16(Bl_ + gb, Bsl + so);
    }
  };
  const int nt = K >> 6;
  stage(0, 0);
  __syncthreads();
  for (int kt = 0; kt < nt; ++kt) {
    const int cur = kt & 1;
    if (kt + 1 < nt) stage(cur ^ 1, (kt + 1) << 6);
    const int co = cur * 4096;
    #pragma unroll
    for (int ks = 0; ks < 2; ++ks) {
      const int cphys = (ks * 32 + kb * 8) ^ ((fr & 7) << 3);
      int oa = co + (wave * 16 + fr) * 64 + cphys;
      bf16x8 ah = *(const bf16x8*)&Ash[oa];
      bf16x8 al = *(const bf16x8*)&Asl[oa];
      #pragma unroll
      for (int j = 0; j < 4; ++j) {
        int ob = co + (j * 16 + fr) * 64 + cphys;
        bf16x8 bh = *(const bf16x8*)&Bsh[ob];
        bf16x8 bl = *(const bf16x8*)&Bsl[ob];
        acc[j] = __builtin_amdgcn_mfma_f32_16x16x32_bf16(ah, bh, acc[j], 0, 0, 0);
        acc[j] = __builtin_amdgcn_mfma_f32_16x16x32_bf16(ah, bl, acc[j], 0, 0, 0);
        acc[j] = __builtin_amdgcn_mfma_f32_16x16x32_bf16(al, bh, acc[j], 0, 0, 0);
      }
    }
    __syncthreads();
  }
  #pragma unroll
  for (int j = 0; j < 4; ++j)
    #pragma unroll
    for (int rg = 0; rg < 4; ++rg) {
      int m = m0 + wave * 16 + kb * 4 + rg;
      int n = n0 + j * 16 + fr;
      if (CADD) {
        float v = xout[(size_t)m * D + n] + acc[j][rg];
        xout[(size_t)m * D + n] = v;
        bfpair p = split_bf(v);
        xho[(size_t)m * D + n] = p.h;
        xlo[(size_t)m * D + n] = p.l;
      } else {
        Cout[(size_t)m * D + n] = acc[j][rg];
      }
    }
}

// causal EMA windowed conv -> split; 256 tiles of 64x64 (40.7 KB smem)
__device__ void causal_phase(char* smem, const float* x, u16* Rh, u16* Rl,
                             float dec, int G) {
  const int t = threadIdx.x;
  for (int tile = blockIdx.x; tile < 256; tile += G) {
    int s0 = (tile >> 4) * 64, d0 = (tile & 15) * 64;
    float (*tl)[64] = (float(*)[64])smem;  // [159][64]
    for (int idx = t; idx < 159 * 64; idx += 256) {
      int rr = idx >> 6, c = idx & 63;
      int gs = s0 - 95 + rr;
      tl[rr][c] = (gs >= 0) ? x[(size_t)gs * D + d0 + c] : 0.f;
    }
    __syncthreads();
    int c = t & 63, r0 = t >> 6;
    for (int rr = r0; rr < 64; rr += 4) {
      float acc = 0.f, w = 1.f - dec;
      int base = rr + 95;
      #pragma unroll 8
      for (int j = 0; j < 96; ++j) { acc += w * tl[base - j][c]; w *= dec; }
      bfpair p = split_bf(acc);
      Rh[(size_t)(s0 + rr) * D + d0 + c] = p.h;
      Rl[(size_t)(s0 + rr) * D + d0 + c] = p.l;
    }
    __syncthreads();
  }
}

// proj GEMM, k-split x16: blocks 0..255 = (mt = b&15, kq = b>>4), one K=64 step
__device__ void proj_phase(char* smem, const u16* xh, const u16* xl,
                           const u16* Bh_, const u16* Bl_, float* pacc) {
  const int t = threadIdx.x;
  const int mt = blockIdx.x & 15, kq = blockIdx.x >> 4;
  const int m0 = mt * 64;
  const int k0 = kq * 64;
  u16* Ash = (u16*)smem;       // 4096 u16
  u16* Asl = Ash + 4096;
  u16* Bsh = Asl + 4096;       // 8192 u16
  u16* Bsl = Bsh + 8192;
  const int wave = t >> 6, lane = t & 63;
  const int fr = lane & 15, kb = lane >> 4;
  const int sr = t >> 3, skc = (t & 7) << 3;
  const int sswz = skc ^ ((sr & 7) << 3);
  f32x4 acc[8];
  #pragma unroll
  for (int j = 0; j < 8; ++j) acc[j] = 0.f;

  #pragma unroll
  for (int it = 0; it < 2; ++it) {
    int r = it * 32 + sr;
    size_t ga = (size_t)(m0 + r) * D + k0 + sswz;
    gl16(xh + ga, Ash + r * 64 + skc);
    gl16(xl + ga, Asl + r * 64 + skc);
  }
  #pragma unroll
  for (int it = 0; it < 4; ++it) {
    int r = it * 32 + sr;
    size_t gb = (size_t)r * D + k0 + sswz;
    gl16(Bh_ + gb, Bsh + r * 64 + skc);
    gl16(Bl_ + gb, Bsl + r * 64 + skc);
  }
  __syncthreads();
  #pragma unroll
  for (int ks = 0; ks < 2; ++ks) {
    const int cphys = (ks * 32 + kb * 8) ^ ((fr & 7) << 3);
    int oa = (wave * 16 + fr) * 64 + cphys;
    bf16x8 ah = *(const bf16x8*)&Ash[oa];
    bf16x8 al = *(const bf16x8*)&Asl[oa];
    #pragma unroll
    for (int j = 0; j < 8; ++j) {
      int ob = (j * 16 + fr) * 64 + cphys;
      bf16x8 bh = *(const bf16x8*)&Bsh[ob];
      bf16x8 bl = *(const bf16x8*)&Bsl[ob];
      acc[j] = __builtin_amdgcn_mfma_f32_16x16x32_bf16(ah, bh, acc[j], 0, 0, 0);
      acc[j] = __builtin_amdgcn_mfma_f32_16x16x32_bf16(ah, bl, acc[j], 0, 0, 0);
      acc[j] = __builtin_amdgcn_mfma_f32_16x16x32_bf16(al, bh, acc[j], 0, 0, 0);
    }
  }
  float* pb = pacc + (size_t)blockIdx.x * 64 * 128;
  #pragma unroll
  for (int j = 0; j < 8; ++j)
    #pragma unroll
    for (int rg = 0; rg < 4; ++rg) {
      int ml = wave * 16 + kb * 4 + rg;
      pb[ml * 128 + j * 16 + fr] = acc[j][rg];
    }
}

// angles for ALL 64 planes in one block (reads cp from previous kernel)
__device__ void angles_all(float* colsum, const float* cp, const float* agw,
                           const float* bang_i, float* trig) {
  const int t = threadIdx.x;
  f32x4 acc = 0.f;
  for (int b = 0; b < 256; ++b)
    acc += *(const f32x4*)(cp + (size_t)b * D + t * 4);
  *(f32x4*)&colsum[t * 4] = acc;
  __syncthreads();
  const int wave = t >> 6, lane = t & 63;
  for (int pp = 0; pp < 16; ++pp) {
    int p = wave * 16 + pp;
    float sum = 0.f;
    #pragma unroll
    for (int q = 0; q < 16; ++q) {
      int d = lane + q * 64;
      sum += colsum[d] * agw[p * D + d];
    }
    #pragma unroll
    for (int off = 32; off; off >>= 1) sum += __shfl_down(sum, off);
    if (lane == 0) {
      float ang = bang_i[p] + 0.1f * (sum * (1.f / (float)S));
      trig[p] = cosf(ang);
      trig[64 + p] = sinf(ang);
    }
  }
}

// ================= kernel wrappers =================
// grid 576: 0..255 gather; 256..383 gate cvt; 384..575 Wp cvt (Wb stays f32)
__global__ __launch_bounds__(256) void fb_gather(const int* tokens, const float* embed,
                                                 float* x, u16* xh, u16* xl, float* cp,
                                                 const float* gatew, u16* gh, u16* gl,
                                                 const float* Wp, u16* Wph, u16* Wpl) {
  if (blockIdx.x < 256) {
    gather_phase(tokens, embed, x, xh, xl, cp);
  } else if (blockIdx.x < 384) {
    cvt2_range(gatew, gh, gl, (size_t)D * D / 4, 256, 128);
  } else {
    cvt2_range(Wp, Wph, Wpl, (size_t)NCYC * 128 * D / 4, 384, 192);
  }
}
__global__ __launch_bounds__(256) void fb_causal(const float* x, u16* Rh, u16* Rl,
                                                 const float* decay) {
  __shared__ __align__(16) char sm[40704];
  causal_phase(sm, x, Rh, Rl, 1.f / (1.f + expf(-decay[0])), gridDim.x);
}
__global__ __launch_bounds__(256) void fb_gate(const u16* Rh, const u16* Rl,
                                               const u16* gh, const u16* gl,
                                               float* x, u16* xh, u16* xl) {
  __shared__ __align__(16) char sm[65536];
  gemm64_dbuf<true>(sm, Rh, Rl, gh, gl, 1024, x, xh, xl, nullptr);
}
// grid 257(+side): blocks 0..255 proj, block 256 angles, 257.. side lm cvt
__global__ __launch_bounds__(256) void fb_proj(const u16* xh, const u16* xl,
                                               const u16* Wph, const u16* Wpl,
                                               const float* cp, const float* agw,
                                               const float* bang_i,
                                               float* pacc, float* trig,
                                               const float* lmw, u16* lm_bf, int chunk) {
  __shared__ __align__(16) char sm[SMEM_BYTES];
  if (blockIdx.x < 256) proj_phase(sm, xh, xl, Wph, Wpl, pacc);
  else if (blockIdx.x == 256) angles_all((float*)sm, cp, agw, bang_i, trig);
  else side_cvt(lmw, lm_bf, chunk, 257);
}

// ======= FUSED epi+back: 256 blocks (4 full rows each) =============================
__global__ __launch_bounds__(256) void fb_epiback(
    const float* __restrict__ pacc, const float* __restrict__ trig,
    const float* __restrict__ Wbf,   // [1024][128] f32, cycle slice
    float* __restrict__ x, u16* __restrict__ xh, u16* __restrict__ xl,
    float* __restrict__ cp, const float* __restrict__ scale,
    const float* __restrict__ shift, const float* __restrict__ nw,
    const float* __restrict__ onorm, u16* __restrict__ xn, int last,
    const float* lmw, u16* lm_bf, int chunk) {
  __shared__ float praw[4][128];
  __shared__ float Arot[4][128];
  __shared__ float sbuf[4];
  if (blockIdx.x >= 256) { side_cvt(lmw, lm_bf, chunk, 256); return; }
  const int t = threadIdx.x;
  const int b = blockIdx.x;
  const int s0 = b * 4;
  const int mt = s0 >> 6;
  const int r64b = s0 & 63;

  // step 1: reduce pacc over 16 k-partials, then rotate (f32 exact)
  #pragma unroll
  for (int ii = 0; ii < 2; ++ii) {
    int idx = t + ii * 256;
    int e = idx >> 7, c = idx & 127;
    float v = 0.f;
    #pragma unroll
    for (int kq = 0; kq < 16; ++kq)
      v += pacc[((size_t)(kq * 16 + mt) * 64 + r64b + e) * 128 + c];
    praw[e][c] = v;
  }
  __syncthreads();
  #pragma unroll
  for (int ii = 0; ii < 2; ++ii) {
    int idx = t + ii * 256;
    int e = idx >> 7, c = idx & 127;
    int p = c & 63;
    float a = praw[e][p], bb = praw[e][64 + p];
    float ca = trig[p], sa = trig[64 + p];
    Arot[e][c] = (c < 64) ? (a * ca - bb * sa) : (a * sa + bb * ca);
  }
  __syncthreads();

  // step 2: back dot (f32) + silu + y; thread owns cols n = t + q*256, all 4 rows
  float acc[4][4];
  #pragma unroll
  for (int e = 0; e < 4; ++e)
    #pragma unroll
    for (int q = 0; q < 4; ++q) acc[e][q] = 0.f;
  const float* wr0 = Wbf + (size_t)t * 128;
  for (int k = 0; k < 128; k += 4) {
    f32x4 a0 = *(const f32x4*)&Arot[0][k];
    f32x4 a1 = *(const f32x4*)&Arot[1][k];
    f32x4 a2 = *(const f32x4*)&Arot[2][k];
    f32x4 a3 = *(const f32x4*)&Arot[3][k];
    #pragma unroll
    for (int q = 0; q < 4; ++q) {
      f32x4 w4 = *(const f32x4*)(wr0 + (size_t)q * 256 * 128 + k);
      #pragma unroll
      for (int u = 0; u < 4; ++u) {
        acc[0][q] += a0[u] * w4[u];
        acc[1][q] += a1[u] * w4[u];
        acc[2][q] += a2[u] * w4[u];
        acc[3][q] += a3[u] * w4[u];
      }
    }
  }
  float xv[4][4], y[4][4];
  float ssp[4] = {0.f, 0.f, 0.f, 0.f};
  #pragma unroll
  for (int q = 0; q < 4; ++q) {
    int n = t + q * 256;
    float scv = scale[n], shv = shift[n];
    #pragma unroll
    for (int e = 0; e < 4; ++e) {
      float xvv = x[(size_t)(s0 + e) * D + n];
      float tt = (xvv + acc[e][q]) * scv + shv;
      float act = tt / (1.f + expf(-tt));
      float yy = act - xvv;
      xv[e][q] = xvv;
      y[e][q] = yy;
      ssp[e] += yy * yy;
    }
  }

  // step 3: per-row rmsnorm factors
  float inv_[4];
  #pragma unroll
  for (int e = 0; e < 4; ++e) {
    float tot = block_sum256(ssp[e], sbuf);
    inv_[e] = rsqrtf(tot * (1.f / (float)D) + EPS);
  }

  // step 4: apply + write + colsum
  float o_[4][4];
  #pragma unroll
  for (int q = 0; q < 4; ++q) {
    int n = t + q * 256;
    float nwv = nw[n];
    float csum = 0.f;
    #pragma unroll
    for (int e = 0; e < 4; ++e) {
      float o = xv[e][q] + y[e][q] * inv_[e] * nwv;
      o_[e][q] = o;
      bfpair p = split_bf(o);
      size_t gi = (size_t)(s0 + e) * D + n;
      x[gi] = o;
      xh[gi] = p.h;
      xl[gi] = p.l;
      csum += o;
    }
    cp[(size_t)b * D + n] = csum;
  }

  // step 5 (last cycle only): fused final rmsnorm -> xn
  if (last) {
    float s2p[4] = {0.f, 0.f, 0.f, 0.f};
    #pragma unroll
    for (int q = 0; q < 4; ++q)
      #pragma unroll
      for (int e = 0; e < 4; ++e) s2p[e] += o_[e][q] * o_[e][q];
    float inv2[4];
    #pragma unroll
    for (int e = 0; e < 4; ++e) {
      float tot2 = block_sum256(s2p[e], sbuf);
      inv2[e] = rsqrtf(tot2 * (1.f / (float)D) + EPS);
    }
    #pragma unroll
    for (int q = 0; q < 4; ++q) {
      int n = t + q * 256;
      float ow = onorm[n];
      #pragma unroll
      for (int e = 0; e < 4; ++e)
        xn[(size_t)(s0 + e) * D + n] = f2bf(o_[e][q] * inv2[e] * ow);
    }
  }
}

// ---------------- lm_head GEMM: 256x128 tile, 512 threads (4Mx2N waves) ------------
// grid: 4748 = 4 m-tiles x 1187 n-tiles; bijective XCD chunk swizzle (q=593, r=4).
template <bool PRECONV>
__global__ __launch_bounds__(512) void k_lm(const u16* __restrict__ A,
                                            const void* __restrict__ Wsrc,
                                            float* __restrict__ out) {
  __shared__ u16 As[256 * 64];   // 32 KB
  __shared__ u16 Bs[128 * 64];   // 16 KB
  const int bid = blockIdx.x;
  const int xcd = bid & 7, off = bid >> 3;
  const int lid = (xcd < 4 ? xcd * 594 : 4 * 594 + (xcd - 4) * 593) + off;
  const int m0 = (lid & 3) * 256;
  const int n0 = (lid >> 2) * 128;
  const int t = threadIdx.x;
  const int wave = t >> 6, lane = t & 63;
  const int wm = (wave >> 1) * 64, wn = (wave & 1) * 64;
  const int fr = lane & 15, kb = lane >> 4;
  const int sr = t >> 3, skc = (t & 7) << 3;      // sr in [0,64)
  const int sswz = skc ^ ((sr & 7) << 3);
  const u16* Wb16 = (const u16*)Wsrc;
  const float* Wf = (const float*)Wsrc;
  f32x4 acc[4][4];
  #pragma unroll
  for (int i = 0; i < 4; ++i)
    #pragma unroll
    for (int j = 0; j < 4; ++j) acc[i][j] = 0.f;

  for (int k0 = 0; k0 < D; k0 += 64) {
    // stage A: 256 rows x 64 k
    #pragma unroll
    for (int it = 0; it < 4; ++it) {
      int r = it * 64 + sr;
      gl16(A + (size_t)(m0 + r) * D + k0 + sswz, As + r * 64 + skc);
    }
    // stage B: 128 rows x 64 k
    if (PRECONV) {
      #pragma unroll
      for (int it = 0; it < 2; ++it) {
        int r = it * 64 + sr;
        gl16(Wb16 + (size_t)(n0 + r) * D + k0 + sswz, Bs + r * 64 + skc);
      }
    } else {
      #pragma unroll
      for (int it = 0; it < 2; ++it) {
        int r = it * 64 + sr;
        const float* src = Wf + (size_t)(n0 + r) * D + k0 + sswz;
        f32x4 v0 = *(const f32x4*)src;
        f32x4 v1 = *(const f32x4*)(src + 4);
        u16 h[8];
        #pragma unroll
        for (int e = 0; e < 4; ++e) { h[e] = f2bf(v0[e]); h[e + 4] = f2bf(v1[e]); }
        *(bf16x8*)&Bs[r * 64 + skc] = *(bf16x8*)h;
      }
    }
    __syncthreads();
    #pragma unroll
    for (int ks = 0; ks < 2; ++ks) {
      const int cphys = (ks * 32 + kb * 8) ^ ((fr & 7) << 3);
      bf16x8 a[4], b[4];
      #pragma unroll
      for (int i = 0; i < 4; ++i) a[i] = *(const bf16x8*)&As[(wm + i * 16 + fr) * 64 + cphys];
      #pragma unroll
      for (int j = 0; j < 4; ++j) b[j] = *(const bf16x8*)&Bs[(wn + j * 16 + fr) * 64 + cphys];
      #pragma unroll
      for (int i = 0; i < 4; ++i)
        #pragma unroll
        for (int j = 0; j < 4; ++j)
          acc[i][j] = __builtin_amdgcn_mfma_f32_16x16x32_bf16(a[i], b[j], acc[i][j], 0, 0, 0);
    }
    __syncthreads();
  }
  #pragma unroll
  for (int i = 0; i < 4; ++i)
    #pragma unroll
    for (int j = 0; j < 4; ++j)
      #pragma unroll
      for (int rg = 0; rg < 4; ++rg) {
        int m = m0 + wm + i * 16 + kb * 4 + rg;
        int n = n0 + wn + j * 16 + fr;
        out[(size_t)m * NV + n] = acc[i][j][rg];
      }
}

extern "C" void kernel_launch(void* const* d_in, const int* in_sizes, int n_in,
                              void* d_out, int out_size, void* d_ws, size_t ws_size,
                              hipStream_t stream) {
  const int* tokens = (const int*)d_in[0];
  const float* embed = (const float*)d_in[1];
  const float* Wp = (const float*)d_in[2];
  const float* Wb = (const float*)d_in[3];
  const float* bang = (const float*)d_in[4];
  const float* agw = (const float*)d_in[5];
  const float* scales = (const float*)d_in[6];
  const float* shifts = (const float*)d_in[7];
  const float* normw = (const float*)d_in[8];
  const float* decay = (const float*)d_in[9];
  const float* gatew = (const float*)d_in[10];
  const float* onorm = (const float*)d_in[11];
  const float* lmw = (const float*)d_in[12];
  float* out = (float*)d_out;

  char* ws = (char*)d_ws;
  const size_t MB = 1u << 20;
  float* x = (float*)ws;                           // 4 MB
  u16* xh = (u16*)(ws + 4 * MB);                   // 2 MB
  u16* xl = (u16*)(ws + 6 * MB);                   // 2 MB
  u16* Rh = (u16*)(ws + 12 * MB);                  // 2 MB
  u16* Rl = (u16*)(ws + 14 * MB);                  // 2 MB
  float* trig = (float*)(ws + 16 * MB);            // 512 B
  float* cp = (float*)(ws + 17 * MB);              // 1 MB
  u16* xn = (u16*)(ws + 20 * MB);                  // 2 MB
  u16* gate_h = (u16*)(ws + 22 * MB);              // 2 MB
  u16* gate_l = (u16*)(ws + 24 * MB);              // 2 MB
  u16* Wp_h = (u16*)(ws + 26 * MB);                // 7 MB
  u16* Wp_l = (u16*)(ws + 33 * MB);                // 7 MB
  float* pacc = (float*)(ws + 54 * MB);            // 8 MB (256 x 64x128 f32)
  u16* lm_bf = (u16*)(ws + 62 * MB);               // 311 MB (optional)

  const size_t lm_elems = (size_t)NV * D;
  bool preconv = ws_size >= 62 * MB + lm_elems * 2;
  const float* side_src = preconv ? lmw : nullptr;
  u16* side_dst = preconv ? lm_bf : nullptr;
  const int gproj = preconv ? 385 : 257;
  const int gside = preconv ? 384 : 256;

  // gather + gate/Wp weight conversions in ONE kernel (side blocks)
  fb_gather<<<576, 256, 0, stream>>>(tokens, embed, x, xh, xl, cp,
                                     gatew, gate_h, gate_l, Wp, Wp_h, Wp_l);
  for (int i = 0; i < NCYC; ++i) {
    const u16* Wph = Wp_h + (size_t)i * 128 * D;
    const u16* Wpl = Wp_l + (size_t)i * 128 * D;
    const float* Wbf = Wb + (size_t)i * D * 128;
    if ((i & 3) == 0) {
      fb_causal<<<256, 256, 0, stream>>>(x, Rh, Rl, decay);
      fb_gate<<<256, 256, 0, stream>>>(Rh, Rl, gate_h, gate_l, x, xh, xl);
    }
    fb_proj<<<gproj, 256, 0, stream>>>(xh, xl, Wph, Wpl, cp, agw, bang + i * 64,
                                       pacc, trig, side_src, side_dst, i * 2);
    fb_epiback<<<gside, 256, 0, stream>>>(pacc, trig, Wbf, x, xh, xl, cp,
                                          scales + i * D, shifts + i * D, normw + i * D,
                                          onorm, xn, (i == NCYC - 1) ? 1 : 0,
                                          side_src, side_dst, i * 2 + 1);
  }

  if (preconv)
    k_lm<true><<<4748, 512, 0, stream>>>(xn, lm_bf, out);
  else
    k_lm<false><<<4748, 512, 0, stream>>>(xn, lmw, out);
}

// Round 21
// 2758.385 us; speedup vs baseline: 1.0116x; 1.0116x over previous
//
#include <hip/hip_runtime.h>

typedef __attribute__((ext_vector_type(4))) float f32x4;
typedef __attribute__((ext_vector_type(8))) short bf16x8;
typedef unsigned short u16;
typedef unsigned int u32;
typedef __attribute__((ext_vector_type(4))) unsigned short u16x4;

#define EPS 1.1920929e-07f
#define S 1024
#define D 1024
#define NV 151936
#define NCYC 28
#define SMEM_BYTES 49152

__device__ __forceinline__ u16 f2bf(float f) {  // RNE
  u32 u = __float_as_uint(f);
  return (u16)((u + 0x7fffu + ((u >> 16) & 1u)) >> 16);
}
__device__ __forceinline__ float bf2f(u16 h) {
  return __uint_as_float((u32)h << 16);
}
struct bfpair { u16 h, l; };
__device__ __forceinline__ bfpair split_bf(float v) {
  bfpair r;
  r.h = f2bf(v);
  r.l = f2bf(v - bf2f(r.h));
  return r;
}

__device__ __forceinline__ void gl16(const void* g, void* s) {
  __builtin_amdgcn_global_load_lds((const __attribute__((address_space(1))) u32*)g,
                                   (__attribute__((address_space(3))) u32*)s, 16, 0, 0);
}

// safe for repeated calls (sync protects sbuf reuse)
__device__ __forceinline__ float block_sum256(float v, float* sbuf) {
  #pragma unroll
  for (int off = 32; off; off >>= 1) v += __shfl_down(v, off);
  int lane = threadIdx.x & 63, w = threadIdx.x >> 6;
  __syncthreads();
  if (lane == 0) sbuf[w] = v;
  __syncthreads();
  return sbuf[0] + sbuf[1] + sbuf[2] + sbuf[3];
}

// split-convert a range with a block sub-grid [blkbase, blkbase+nblk)
__device__ void cvt2_range(const float* __restrict__ src, u16* __restrict__ dh,
                           u16* __restrict__ dl, size_t n4, int blkbase, int nblk) {
  for (size_t i = (size_t)(blockIdx.x - blkbase) * 256 + threadIdx.x; i < n4;
       i += (size_t)nblk * 256) {
    f32x4 v = ((const f32x4*)src)[i];
    u16x4 oh, ol;
    #pragma unroll
    for (int e = 0; e < 4; ++e) { bfpair p = split_bf(v[e]); oh[e] = p.h; ol[e] = p.l; }
    ((u16x4*)dh)[i] = oh;
    ((u16x4*)dl)[i] = ol;
  }
}

// side-work: convert one chunk of lm weights (chunk in [0, NCYC*2))
__device__ void side_cvt(const float* __restrict__ src, u16* __restrict__ dst,
                         int chunk, int blkbase) {
  if (!src) return;
  const size_t n4 = (size_t)NV * D / 4;
  const size_t per = (n4 + (size_t)(NCYC * 2) - 1) / (size_t)(NCYC * 2);
  size_t lo = (size_t)chunk * per;
  size_t hi = lo + per;
  if (hi > n4) hi = n4;
  const size_t nb = (size_t)(gridDim.x - blkbase);
  for (size_t i = lo + (size_t)(blockIdx.x - blkbase) * 256 + threadIdx.x; i < hi;
       i += nb * 256) {
    f32x4 v = ((const f32x4*)src)[i];
    u16x4 o;
    #pragma unroll
    for (int e = 0; e < 4; ++e) o[e] = f2bf(v[e]);
    ((u16x4*)dst)[i] = o;
  }
}

// ================= device phases =================

// gather + initial colpart; blocks 0..255
__device__ void gather_phase(const int* tokens, const float* embed,
                             float* x, u16* xh, u16* xl, float* cp) {
  const int t = threadIdx.x;
  f32x4 creg = 0.f;
  for (int rr = 0; rr < 4; ++rr) {
    int s = blockIdx.x * 4 + rr;
    int tok = tokens[s];
    f32x4 v = ((const f32x4*)(embed + (size_t)tok * D))[t];
    u16x4 oh, ol;
    #pragma unroll
    for (int e = 0; e < 4; ++e) { bfpair p = split_bf(v[e]); oh[e] = p.h; ol[e] = p.l; }
    ((f32x4*)(x + (size_t)s * D))[t] = v;
    ((u16x4*)(xh + (size_t)s * D))[t] = oh;
    ((u16x4*)(xl + (size_t)s * D))[t] = ol;
    creg += v;
  }
  *(f32x4*)(cp + (size_t)blockIdx.x * D + t * 4) = creg;
}

// 64x64-tile split-bf16 GEMM, 256 tiles, DOUBLE-buffered (gate; 1 block/CU grid)
template <bool CADD>
__device__ void gemm64_dbuf(char* smem, const u16* Ah_, const u16* Al_,
                            const u16* Bh_, const u16* Bl_, int K,
                            float* xout, u16* xho, u16* xlo, float* Cout) {
  const int t = threadIdx.x;
  u16* Ash = (u16*)smem;          // [2][4096] each operand
  u16* Asl = Ash + 8192;
  u16* Bsh = Asl + 8192;
  u16* Bsl = Bsh + 8192;
  const int wave = t >> 6, lane = t & 63;
  const int fr = lane & 15, kb = lane >> 4;
  const int sr = t >> 3, skc = (t & 7) << 3;
  const int sswz = skc ^ ((sr & 7) << 3);
  const int m0 = (blockIdx.x >> 4) * 64, n0 = (blockIdx.x & 15) * 64;
  f32x4 acc[4];
  #pragma unroll
  for (int j = 0; j < 4; ++j) acc[j] = 0.f;

  auto stage = [&](int buf, int k0) {
    #pragma unroll
    for (int it = 0; it < 2; ++it) {
      int r = it * 32 + sr;
      size_t ga = (size_t)(m0 + r) * K + k0 + sswz;
      size_t gb = (size_t)(n0 + r) * K + k0 + sswz;
      int so = buf * 4096 + r * 64 + skc;
      gl16(Ah_ + ga, Ash + so);
      gl16(Al_ + ga, Asl + so);
      gl16(Bh_ + gb, Bsh + so);
      gl16(Bl_ + gb, Bsl + so);
    }
  };
  const int nt = K >> 6;
  stage(0, 0);
  __syncthreads();
  for (int kt = 0; kt < nt; ++kt) {
    const int cur = kt & 1;
    if (kt + 1 < nt) stage(cur ^ 1, (kt + 1) << 6);
    const int co = cur * 4096;
    #pragma unroll
    for (int ks = 0; ks < 2; ++ks) {
      const int cphys = (ks * 32 + kb * 8) ^ ((fr & 7) << 3);
      int oa = co + (wave * 16 + fr) * 64 + cphys;
      bf16x8 ah = *(const bf16x8*)&Ash[oa];
      bf16x8 al = *(const bf16x8*)&Asl[oa];
      #pragma unroll
      for (int j = 0; j < 4; ++j) {
        int ob = co + (j * 16 + fr) * 64 + cphys;
        bf16x8 bh = *(const bf16x8*)&Bsh[ob];
        bf16x8 bl = *(const bf16x8*)&Bsl[ob];
        acc[j] = __builtin_amdgcn_mfma_f32_16x16x32_bf16(ah, bh, acc[j], 0, 0, 0);
        acc[j] = __builtin_amdgcn_mfma_f32_16x16x32_bf16(ah, bl, acc[j], 0, 0, 0);
        acc[j] = __builtin_amdgcn_mfma_f32_16x16x32_bf16(al, bh, acc[j], 0, 0, 0);
      }
    }
    __syncthreads();
  }
  #pragma unroll
  for (int j = 0; j < 4; ++j)
    #pragma unroll
    for (int rg = 0; rg < 4; ++rg) {
      int m = m0 + wave * 16 + kb * 4 + rg;
      int n = n0 + j * 16 + fr;
      if (CADD) {
        float v = xout[(size_t)m * D + n] + acc[j][rg];
        xout[(size_t)m * D + n] = v;
        bfpair p = split_bf(v);
        xho[(size_t)m * D + n] = p.h;
        xlo[(size_t)m * D + n] = p.l;
      } else {
        Cout[(size_t)m * D + n] = acc[j][rg];
      }
    }
}

// causal EMA windowed conv -> split; 256 tiles of 64x64 (40.7 KB smem)
__device__ void causal_phase(char* smem, const float* x, u16* Rh, u16* Rl,
                             float dec, int G) {
  const int t = threadIdx.x;
  for (int tile = blockIdx.x; tile < 256; tile += G) {
    int s0 = (tile >> 4) * 64, d0 = (tile & 15) * 64;
    float (*tl)[64] = (float(*)[64])smem;  // [159][64]
    for (int idx = t; idx < 159 * 64; idx += 256) {
      int rr = idx >> 6, c = idx & 63;
      int gs = s0 - 95 + rr;
      tl[rr][c] = (gs >= 0) ? x[(size_t)gs * D + d0 + c] : 0.f;
    }
    __syncthreads();
    int c = t & 63, r0 = t >> 6;
    for (int rr = r0; rr < 64; rr += 4) {
      float acc = 0.f, w = 1.f - dec;
      int base = rr + 95;
      #pragma unroll 8
      for (int j = 0; j < 96; ++j) { acc += w * tl[base - j][c]; w *= dec; }
      bfpair p = split_bf(acc);
      Rh[(size_t)(s0 + rr) * D + d0 + c] = p.h;
      Rl[(size_t)(s0 + rr) * D + d0 + c] = p.l;
    }
    __syncthreads();
  }
}

// proj GEMM, k-split x16: blocks 0..255 = (mt = b&15, kq = b>>4), one K=64 step
__device__ void proj_phase(char* smem, const u16* xh, const u16* xl,
                           const u16* Bh_, const u16* Bl_, float* pacc) {
  const int t = threadIdx.x;
  const int mt = blockIdx.x & 15, kq = blockIdx.x >> 4;
  const int m0 = mt * 64;
  const int k0 = kq * 64;
  u16* Ash = (u16*)smem;       // 4096 u16
  u16* Asl = Ash + 4096;
  u16* Bsh = Asl + 4096;       // 8192 u16
  u16* Bsl = Bsh + 8192;
  const int wave = t >> 6, lane = t & 63;
  const int fr = lane & 15, kb = lane >> 4;
  const int sr = t >> 3, skc = (t & 7) << 3;
  const int sswz = skc ^ ((sr & 7) << 3);
  f32x4 acc[8];
  #pragma unroll
  for (int j = 0; j < 8; ++j) acc[j] = 0.f;

  #pragma unroll
  for (int it = 0; it < 2; ++it) {
    int r = it * 32 + sr;
    size_t ga = (size_t)(m0 + r) * D + k0 + sswz;
    gl16(xh + ga, Ash + r * 64 + skc);
    gl16(xl + ga, Asl + r * 64 + skc);
  }
  #pragma unroll
  for (int it = 0; it < 4; ++it) {
    int r = it * 32 + sr;
    size_t gb = (size_t)r * D + k0 + sswz;
    gl16(Bh_ + gb, Bsh + r * 64 + skc);
    gl16(Bl_ + gb, Bsl + r * 64 + skc);
  }
  __syncthreads();
  #pragma unroll
  for (int ks = 0; ks < 2; ++ks) {
    const int cphys = (ks * 32 + kb * 8) ^ ((fr & 7) << 3);
    int oa = (wave * 16 + fr) * 64 + cphys;
    bf16x8 ah = *(const bf16x8*)&Ash[oa];
    bf16x8 al = *(const bf16x8*)&Asl[oa];
    #pragma unroll
    for (int j = 0; j < 8; ++j) {
      int ob = (j * 16 + fr) * 64 + cphys;
      bf16x8 bh = *(const bf16x8*)&Bsh[ob];
      bf16x8 bl = *(const bf16x8*)&Bsl[ob];
      acc[j] = __builtin_amdgcn_mfma_f32_16x16x32_bf16(ah, bh, acc[j], 0, 0, 0);
      acc[j] = __builtin_amdgcn_mfma_f32_16x16x32_bf16(ah, bl, acc[j], 0, 0, 0);
      acc[j] = __builtin_amdgcn_mfma_f32_16x16x32_bf16(al, bh, acc[j], 0, 0, 0);
    }
  }
  float* pb = pacc + (size_t)blockIdx.x * 64 * 128;
  #pragma unroll
  for (int j = 0; j < 8; ++j)
    #pragma unroll
    for (int rg = 0; rg < 4; ++rg) {
      int ml = wave * 16 + kb * 4 + rg;
      pb[ml * 128 + j * 16 + fr] = acc[j][rg];
    }
}

// angles for ALL 64 planes in one block (reads cp from previous kernel)
__device__ void angles_all(float* colsum, const float* cp, const float* agw,
                           const float* bang_i, float* trig) {
  const int t = threadIdx.x;
  f32x4 acc = 0.f;
  for (int b = 0; b < 256; ++b)
    acc += *(const f32x4*)(cp + (size_t)b * D + t * 4);
  *(f32x4*)&colsum[t * 4] = acc;
  __syncthreads();
  const int wave = t >> 6, lane = t & 63;
  for (int pp = 0; pp < 16; ++pp) {
    int p = wave * 16 + pp;
    float sum = 0.f;
    #pragma unroll
    for (int q = 0; q < 16; ++q) {
      int d = lane + q * 64;
      sum += colsum[d] * agw[p * D + d];
    }
    #pragma unroll
    for (int off = 32; off; off >>= 1) sum += __shfl_down(sum, off);
    if (lane == 0) {
      float ang = bang_i[p] + 0.1f * (sum * (1.f / (float)S));
      trig[p] = cosf(ang);
      trig[64 + p] = sinf(ang);
    }
  }
}

// ================= kernel wrappers =================
// grid 576: 0..255 gather; 256..383 gate cvt; 384..575 Wp cvt (Wb stays f32)
__global__ __launch_bounds__(256) void fb_gather(const int* tokens, const float* embed,
                                                 float* x, u16* xh, u16* xl, float* cp,
                                                 const float* gatew, u16* gh, u16* gl,
                                                 const float* Wp, u16* Wph, u16* Wpl) {
  if (blockIdx.x < 256) {
    gather_phase(tokens, embed, x, xh, xl, cp);
  } else if (blockIdx.x < 384) {
    cvt2_range(gatew, gh, gl, (size_t)D * D / 4, 256, 128);
  } else {
    cvt2_range(Wp, Wph, Wpl, (size_t)NCYC * 128 * D / 4, 384, 192);
  }
}
__global__ __launch_bounds__(256) void fb_causal(const float* x, u16* Rh, u16* Rl,
                                                 const float* decay) {
  __shared__ __align__(16) char sm[40704];
  causal_phase(sm, x, Rh, Rl, 1.f / (1.f + expf(-decay[0])), gridDim.x);
}
__global__ __launch_bounds__(256) void fb_gate(const u16* Rh, const u16* Rl,
                                               const u16* gh, const u16* gl,
                                               float* x, u16* xh, u16* xl) {
  __shared__ __align__(16) char sm[65536];
  gemm64_dbuf<true>(sm, Rh, Rl, gh, gl, 1024, x, xh, xl, nullptr);
}
// grid 257(+side): blocks 0..255 proj, block 256 angles, 257.. side lm cvt
__global__ __launch_bounds__(256) void fb_proj(const u16* xh, const u16* xl,
                                               const u16* Wph, const u16* Wpl,
                                               const float* cp, const float* agw,
                                               const float* bang_i,
                                               float* pacc, float* trig,
                                               const float* lmw, u16* lm_bf, int chunk) {
  __shared__ __align__(16) char sm[SMEM_BYTES];
  if (blockIdx.x < 256) proj_phase(sm, xh, xl, Wph, Wpl, pacc);
  else if (blockIdx.x == 256) angles_all((float*)sm, cp, agw, bang_i, trig);
  else side_cvt(lmw, lm_bf, chunk, 257);
}

// ======= FUSED epi+back: 256 blocks (4 full rows each) =============================
__global__ __launch_bounds__(256) void fb_epiback(
    const float* __restrict__ pacc, const float* __restrict__ trig,
    const float* __restrict__ Wbf,   // [1024][128] f32, cycle slice
    float* __restrict__ x, u16* __restrict__ xh, u16* __restrict__ xl,
    float* __restrict__ cp, const float* __restrict__ scale,
    const float* __restrict__ shift, const float* __restrict__ nw,
    const float* __restrict__ onorm, u16* __restrict__ xn, int last,
    const float* lmw, u16* lm_bf, int chunk) {
  __shared__ float praw[4][128];
  __shared__ float Arot[4][128];
  __shared__ float sbuf[4];
  if (blockIdx.x >= 256) { side_cvt(lmw, lm_bf, chunk, 256); return; }
  const int t = threadIdx.x;
  const int b = blockIdx.x;
  const int s0 = b * 4;
  const int mt = s0 >> 6;
  const int r64b = s0 & 63;

  // step 1: reduce pacc over 16 k-partials, then rotate (f32 exact)
  #pragma unroll
  for (int ii = 0; ii < 2; ++ii) {
    int idx = t + ii * 256;
    int e = idx >> 7, c = idx & 127;
    float v = 0.f;
    #pragma unroll
    for (int kq = 0; kq < 16; ++kq)
      v += pacc[((size_t)(kq * 16 + mt) * 64 + r64b + e) * 128 + c];
    praw[e][c] = v;
  }
  __syncthreads();
  #pragma unroll
  for (int ii = 0; ii < 2; ++ii) {
    int idx = t + ii * 256;
    int e = idx >> 7, c = idx & 127;
    int p = c & 63;
    float a = praw[e][p], bb = praw[e][64 + p];
    float ca = trig[p], sa = trig[64 + p];
    Arot[e][c] = (c < 64) ? (a * ca - bb * sa) : (a * sa + bb * ca);
  }
  __syncthreads();

  // step 2: back dot (f32) + silu + y; thread owns cols n = t + q*256, all 4 rows
  float acc[4][4];
  #pragma unroll
  for (int e = 0; e < 4; ++e)
    #pragma unroll
    for (int q = 0; q < 4; ++q) acc[e][q] = 0.f;
  const float* wr0 = Wbf + (size_t)t * 128;
  for (int k = 0; k < 128; k += 4) {
    f32x4 a0 = *(const f32x4*)&Arot[0][k];
    f32x4 a1 = *(const f32x4*)&Arot[1][k];
    f32x4 a2 = *(const f32x4*)&Arot[2][k];
    f32x4 a3 = *(const f32x4*)&Arot[3][k];
    #pragma unroll
    for (int q = 0; q < 4; ++q) {
      f32x4 w4 = *(const f32x4*)(wr0 + (size_t)q * 256 * 128 + k);
      #pragma unroll
      for (int u = 0; u < 4; ++u) {
        acc[0][q] += a0[u] * w4[u];
        acc[1][q] += a1[u] * w4[u];
        acc[2][q] += a2[u] * w4[u];
        acc[3][q] += a3[u] * w4[u];
      }
    }
  }
  float xv[4][4], y[4][4];
  float ssp[4] = {0.f, 0.f, 0.f, 0.f};
  #pragma unroll
  for (int q = 0; q < 4; ++q) {
    int n = t + q * 256;
    float scv = scale[n], shv = shift[n];
    #pragma unroll
    for (int e = 0; e < 4; ++e) {
      float xvv = x[(size_t)(s0 + e) * D + n];
      float tt = (xvv + acc[e][q]) * scv + shv;
      float act = tt / (1.f + expf(-tt));
      float yy = act - xvv;
      xv[e][q] = xvv;
      y[e][q] = yy;
      ssp[e] += yy * yy;
    }
  }

  // step 3: per-row rmsnorm factors
  float inv_[4];
  #pragma unroll
  for (int e = 0; e < 4; ++e) {
    float tot = block_sum256(ssp[e], sbuf);
    inv_[e] = rsqrtf(tot * (1.f / (float)D) + EPS);
  }

  // step 4: apply + write + colsum
  float o_[4][4];
  #pragma unroll
  for (int q = 0; q < 4; ++q) {
    int n = t + q * 256;
    float nwv = nw[n];
    float csum = 0.f;
    #pragma unroll
    for (int e = 0; e < 4; ++e) {
      float o = xv[e][q] + y[e][q] * inv_[e] * nwv;
      o_[e][q] = o;
      bfpair p = split_bf(o);
      size_t gi = (size_t)(s0 + e) * D + n;
      x[gi] = o;
      xh[gi] = p.h;
      xl[gi] = p.l;
      csum += o;
    }
    cp[(size_t)b * D + n] = csum;
  }

  // step 5 (last cycle only): fused final rmsnorm -> xn
  if (last) {
    float s2p[4] = {0.f, 0.f, 0.f, 0.f};
    #pragma unroll
    for (int q = 0; q < 4; ++q)
      #pragma unroll
      for (int e = 0; e < 4; ++e) s2p[e] += o_[e][q] * o_[e][q];
    float inv2[4];
    #pragma unroll
    for (int e = 0; e < 4; ++e) {
      float tot2 = block_sum256(s2p[e], sbuf);
      inv2[e] = rsqrtf(tot2 * (1.f / (float)D) + EPS);
    }
    #pragma unroll
    for (int q = 0; q < 4; ++q) {
      int n = t + q * 256;
      float ow = onorm[n];
      #pragma unroll
      for (int e = 0; e < 4; ++e)
        xn[(size_t)(s0 + e) * D + n] = f2bf(o_[e][q] * inv2[e] * ow);
    }
  }
}

// ---------------- lm_head GEMM, single-buffered LDS + T2 swizzle, XCD swizzle ------
// grid: 9496 = 8 m-tiles x 1187 n-tiles (1-D). Proven 565 us.
template <bool PRECONV>
__global__ __launch_bounds__(256) void k_lm(const u16* __restrict__ A,
                                            const void* __restrict__ Wsrc,
                                            float* __restrict__ out) {
  __shared__ u16 As[128 * 64];
  __shared__ u16 Bs[128 * 64];
  const int bid = blockIdx.x;
  const int lid = (bid & 7) * 1187 + (bid >> 3);  // bijective: 9496 = 8*1187
  const int m0 = (lid & 7) * 128;
  const int n0 = (lid >> 3) * 128;
  const int t = threadIdx.x;
  const int wave = t >> 6, lane = t & 63;
  const int wm = (wave >> 1) * 64, wn = (wave & 1) * 64;
  const int fr = lane & 15, kb = lane >> 4;
  const int sr = t >> 3, skc = (t & 7) << 3;
  const int sswz = skc ^ ((sr & 7) << 3);
  const u16* Wb16 = (const u16*)Wsrc;
  const float* Wf = (const float*)Wsrc;
  f32x4 acc[4][4];
  #pragma unroll
  for (int i = 0; i < 4; ++i)
    #pragma unroll
    for (int j = 0; j < 4; ++j) acc[i][j] = 0.f;

  for (int k0 = 0; k0 < D; k0 += 64) {
    #pragma unroll
    for (int it = 0; it < 4; ++it) {
      int r = it * 32 + sr;
      gl16(A + (size_t)(m0 + r) * D + k0 + sswz, As + r * 64 + skc);
    }
    if (PRECONV) {
      #pragma unroll
      for (int it = 0; it < 4; ++it) {
        int r = it * 32 + sr;
        gl16(Wb16 + (size_t)(n0 + r) * D + k0 + sswz, Bs + r * 64 + skc);
      }
    } else {
      #pragma unroll
      for (int it = 0; it < 4; ++it) {
        int r = it * 32 + sr;
        const float* src = Wf + (size_t)(n0 + r) * D + k0 + sswz;
        f32x4 v0 = *(const f32x4*)src;
        f32x4 v1 = *(const f32x4*)(src + 4);
        u16 h[8];
        #pragma unroll
        for (int e = 0; e < 4; ++e) { h[e] = f2bf(v0[e]); h[e + 4] = f2bf(v1[e]); }
        *(bf16x8*)&Bs[r * 64 + skc] = *(bf16x8*)h;
      }
    }
    __syncthreads();
    #pragma unroll
    for (int ks = 0; ks < 2; ++ks) {
      const int cphys = (ks * 32 + kb * 8) ^ ((fr & 7) << 3);
      bf16x8 a[4], b[4];
      #pragma unroll
      for (int i = 0; i < 4; ++i) a[i] = *(const bf16x8*)&As[(wm + i * 16 + fr) * 64 + cphys];
      #pragma unroll
      for (int j = 0; j < 4; ++j) b[j] = *(const bf16x8*)&Bs[(wn + j * 16 + fr) * 64 + cphys];
      #pragma unroll
      for (int i = 0; i < 4; ++i)
        #pragma unroll
        for (int j = 0; j < 4; ++j)
          acc[i][j] = __builtin_amdgcn_mfma_f32_16x16x32_bf16(a[i], b[j], acc[i][j], 0, 0, 0);
    }
    __syncthreads();
  }
  #pragma unroll
  for (int i = 0; i < 4; ++i)
    #pragma unroll
    for (int j = 0; j < 4; ++j)
      #pragma unroll
      for (int rg = 0; rg < 4; ++rg) {
        int m = m0 + wm + i * 16 + kb * 4 + rg;
        int n = n0 + wn + j * 16 + fr;
        out[(size_t)m * NV + n] = acc[i][j][rg];
      }
}

extern "C" void kernel_launch(void* const* d_in, const int* in_sizes, int n_in,
                              void* d_out, int out_size, void* d_ws, size_t ws_size,
                              hipStream_t stream) {
  const int* tokens = (const int*)d_in[0];
  const float* embed = (const float*)d_in[1];
  const float* Wp = (const float*)d_in[2];
  const float* Wb = (const float*)d_in[3];
  const float* bang = (const float*)d_in[4];
  const float* agw = (const float*)d_in[5];
  const float* scales = (const float*)d_in[6];
  const float* shifts = (const float*)d_in[7];
  const float* normw = (const float*)d_in[8];
  const float* decay = (const float*)d_in[9];
  const float* gatew = (const float*)d_in[10];
  const float* onorm = (const float*)d_in[11];
  const float* lmw = (const float*)d_in[12];
  float* out = (float*)d_out;

  char* ws = (char*)d_ws;
  const size_t MB = 1u << 20;
  float* x = (float*)ws;                           // 4 MB
  u16* xh = (u16*)(ws + 4 * MB);                   // 2 MB
  u16* xl = (u16*)(ws + 6 * MB);                   // 2 MB
  u16* Rh = (u16*)(ws + 12 * MB);                  // 2 MB
  u16* Rl = (u16*)(ws + 14 * MB);                  // 2 MB
  float* trig = (float*)(ws + 16 * MB);            // 512 B
  float* cp = (float*)(ws + 17 * MB);              // 1 MB
  u16* xn = (u16*)(ws + 20 * MB);                  // 2 MB
  u16* gate_h = (u16*)(ws + 22 * MB);              // 2 MB
  u16* gate_l = (u16*)(ws + 24 * MB);              // 2 MB
  u16* Wp_h = (u16*)(ws + 26 * MB);                // 7 MB
  u16* Wp_l = (u16*)(ws + 33 * MB);                // 7 MB
  float* pacc = (float*)(ws + 54 * MB);            // 8 MB (256 x 64x128 f32)
  u16* lm_bf = (u16*)(ws + 62 * MB);               // 311 MB (optional)

  const size_t lm_elems = (size_t)NV * D;
  bool preconv = ws_size >= 62 * MB + lm_elems * 2;
  const float* side_src = preconv ? lmw : nullptr;
  u16* side_dst = preconv ? lm_bf : nullptr;
  const int gproj = preconv ? 385 : 257;
  const int gside = preconv ? 384 : 256;

  // gather + gate/Wp weight conversions in ONE kernel (side blocks)
  fb_gather<<<576, 256, 0, stream>>>(tokens, embed, x, xh, xl, cp,
                                     gatew, gate_h, gate_l, Wp, Wp_h, Wp_l);
  for (int i = 0; i < NCYC; ++i) {
    const u16* Wph = Wp_h + (size_t)i * 128 * D;
    const u16* Wpl = Wp_l + (size_t)i * 128 * D;
    const float* Wbf = Wb + (size_t)i * D * 128;
    if ((i & 3) == 0) {
      fb_causal<<<256, 256, 0, stream>>>(x, Rh, Rl, decay);
      fb_gate<<<256, 256, 0, stream>>>(Rh, Rl, gate_h, gate_l, x, xh, xl);
    }
    fb_proj<<<gproj, 256, 0, stream>>>(xh, xl, Wph, Wpl, cp, agw, bang + i * 64,
                                       pacc, trig, side_src, side_dst, i * 2);
    fb_epiback<<<gside, 256, 0, stream>>>(pacc, trig, Wbf, x, xh, xl, cp,
                                          scales + i * D, shifts + i * D, normw + i * D,
                                          onorm, xn, (i == NCYC - 1) ? 1 : 0,
                                          side_src, side_dst, i * 2 + 1);
  }

  if (preconv)
    k_lm<true><<<9496, 256, 0, stream>>>(xn, lm_bf, out);
  else
    k_lm<false><<<9496, 256, 0, stream>>>(xn, lmw, out);
}